// Round 4
// baseline (423.610 us; speedup 1.0000x reference)
//
#include <hip/hip_runtime.h>
#include <hip/hip_bf16.h>

typedef unsigned short u16;
typedef __attribute__((ext_vector_type(8))) __bf16 bf16x8;
typedef __attribute__((ext_vector_type(4))) float f32x4;

#define DEV __device__ __forceinline__

DEV u16 f2bf(float f) {
  union { float f; unsigned int u; } v; v.f = f;
  unsigned int x = v.u;
  return (u16)((x + 0x7fffu + ((x >> 16) & 1u)) >> 16);  // RNE
}

DEV void gload_lds16(const u16* g, u16* l) {
  __builtin_amdgcn_global_load_lds(
      (__attribute__((address_space(1))) void*)(g),
      (__attribute__((address_space(3))) void*)(l), 16, 0, 0);
}

// ---------------- LayerNorm + cast to bf16 ----------------
template <int NV>
__global__ __launch_bounds__(256) void ln_cast(const float* __restrict__ x,
                                               const float* __restrict__ g,
                                               const float* __restrict__ b,
                                               u16* __restrict__ out, int C) {
  int row = blockIdx.x;
  int tid = threadIdx.x;
  const float4* xr = (const float4*)(x + (size_t)row * C);
  float4 v[NV];
  float s = 0.f, ss = 0.f;
#pragma unroll
  for (int i = 0; i < NV; i++) {
    v[i] = xr[tid + i * 256];
    s += v[i].x + v[i].y + v[i].z + v[i].w;
    ss += v[i].x * v[i].x + v[i].y * v[i].y + v[i].z * v[i].z + v[i].w * v[i].w;
  }
#pragma unroll
  for (int off = 32; off > 0; off >>= 1) {
    s += __shfl_down(s, off);
    ss += __shfl_down(ss, off);
  }
  __shared__ float red[8];
  int wv = tid >> 6;
  if ((tid & 63) == 0) { red[wv] = s; red[4 + wv] = ss; }
  __syncthreads();
  float S = red[0] + red[1] + red[2] + red[3];
  float SS = red[4] + red[5] + red[6] + red[7];
  float mu = S / C;
  float rstd = rsqrtf(SS / C - mu * mu + 1e-5f);
  const float4* gr = (const float4*)g;
  const float4* br = (const float4*)b;
  ushort4* orow = (ushort4*)(out + (size_t)row * C);
#pragma unroll
  for (int i = 0; i < NV; i++) {
    int gi = tid + i * 256;
    float4 gv = gr[gi], bv = br[gi];
    ushort4 o;
    o.x = f2bf((v[i].x - mu) * rstd * gv.x + bv.x);
    o.y = f2bf((v[i].y - mu) * rstd * gv.y + bv.y);
    o.z = f2bf((v[i].z - mu) * rstd * gv.z + bv.z);
    o.w = f2bf((v[i].w - mu) * rstd * gv.w + bv.w);
    orow[gi] = o;
  }
}

// ---------------- transpose + cast f32 -> bf16 ----------------
__global__ __launch_bounds__(256) void transpose_cast(const float* __restrict__ in,
                                                      u16* __restrict__ out,
                                                      int K, int N) {
  __shared__ float t[32][33];
  int tx = threadIdx.x & 31, ty = threadIdx.x >> 5;
  int n0 = blockIdx.x * 32, k0 = blockIdx.y * 32;
#pragma unroll
  for (int i = 0; i < 32; i += 8)
    t[ty + i][tx] = in[(size_t)(k0 + ty + i) * N + n0 + tx];
  __syncthreads();
#pragma unroll
  for (int i = 0; i < 32; i += 8)
    out[(size_t)(n0 + ty + i) * K + k0 + tx] = f2bf(t[tx][ty + i]);
}

// ---------------- build VT[bh][128][1024] from KV ----------------
__global__ __launch_bounds__(256) void build_vt(const u16* __restrict__ KV,
                                                u16* __restrict__ VT) {
  __shared__ u16 t[32][33];
  int bh = blockIdx.z, b = bh >> 4, h = bh & 15;
  int d0 = blockIdx.x * 32, s0 = blockIdx.y * 32;
  int tx = threadIdx.x & 31, ty = threadIdx.x >> 5;
  const u16* src = KV + (size_t)(b * 1024) * 4096 + 2048 + h * 128;
#pragma unroll
  for (int i = 0; i < 32; i += 8)
    t[ty + i][tx] = src[(size_t)(s0 + ty + i) * 4096 + d0 + tx];
  __syncthreads();
  u16* dst = VT + (size_t)bh * (128 * 1024);
#pragma unroll
  for (int i = 0; i < 32; i += 8)
    dst[(size_t)(d0 + ty + i) * 1024 + s0 + tx] = t[tx][ty + i];
}

DEV void storeC(u16* C, size_t idx, float v) { C[idx] = f2bf(v); }
DEV void storeC(float* C, size_t idx, float v) { C[idx] = v; }

// ---------------- pipelined GEMM: C[M,N] = oscale * A[M,K] * BT[N,K]^T ----------------
// 3 LDS buffers, BK=32, counted vmcnt (never 0 in main loop) + raw s_barrier.
// Per wave: 128x64 output = acc[8][4] fragments; WM x WN wave grid.
template <typename OutT, int BM, int BN, int WM, int WN>
__global__ __launch_bounds__(WM * WN * 64, 2) void gemm_pipe(
    const u16* __restrict__ A, const u16* __restrict__ BT, OutT* __restrict__ C,
    int M, int N, int K, float oscale) {
  constexpr int THREADS = WM * WN * 64;
  constexpr int BK = 32;
  constexpr int AL = (BM * 4) / THREADS;  // A stage loads / thread / K-tile
  constexpr int BL = (BN * 4) / THREADS;  // B stage loads / thread / K-tile
  constexpr int LPT = AL + BL;
  __shared__ __attribute__((aligned(16))) u16 As[3][BM * BK];
  __shared__ __attribute__((aligned(16))) u16 Bs[3][BN * BK];

  int tilesN = N / BN;
  int bm = (blockIdx.x / tilesN) * BM;
  int bn = (blockIdx.x % tilesN) * BN;
  int tid = threadIdx.x, lane = tid & 63, w = tid >> 6;
  int wr = w / WN, wc = w % WN;
  int fr = lane & 15, g = lane >> 4;

  const u16* Ab = A + (size_t)bm * K + (tid & 3) * 8;
  const u16* Bb = BT + (size_t)bn * K + (tid & 3) * 8;
  int row0 = tid >> 2;

  auto stageA = [&](int kt, int buf) {
#pragma unroll
    for (int j = 0; j < AL; j++)
      gload_lds16(Ab + (size_t)(row0 + j * (THREADS / 4)) * K + kt,
                  &As[buf][w * 512 + j * THREADS * 8]);
  };
  auto stageB = [&](int kt, int buf) {
#pragma unroll
    for (int j = 0; j < BL; j++)
      gload_lds16(Bb + (size_t)(row0 + j * (THREADS / 4)) * K + kt,
                  &Bs[buf][w * 512 + j * THREADS * 8]);
  };

  f32x4 acc[8][4] = {};
  const int NT = K / BK;

  // prologue: stage t=0 (buf0), t=1 (buf1); wait t0 landed (t1 in flight)
  stageA(0, 0); stageB(0, 0);
  stageA(BK, 1); stageB(BK, 1);
  asm volatile("s_waitcnt vmcnt(%0)" ::"n"(LPT) : "memory");
  __builtin_amdgcn_s_barrier();
  __builtin_amdgcn_sched_barrier(0);

  int cur = 0;
  for (int t = 0; t < NT; ++t) {
    int nxt = cur + 1; if (nxt == 3) nxt = 0;
    int pre = nxt + 1; if (pre == 3) pre = 0;
    // issue prefetch of K-tile t+2 into the buffer freed at iteration t-1
    if (t + 2 < NT) { stageA((t + 2) * BK, pre); stageB((t + 2) * BK, pre); }

    const u16* as = &As[cur][0];
    const u16* bs = &Bs[cur][0];
    bf16x8 afrag[4], bfrag[4];
#pragma unroll
    for (int n = 0; n < 4; n++)
      bfrag[n] = *(const bf16x8*)&bs[(wc * 64 + n * 16 + fr) * BK + g * 8];
#pragma unroll
    for (int m = 0; m < 4; m++)
      afrag[m] = *(const bf16x8*)&as[(wr * 128 + m * 16 + fr) * BK + g * 8];
    __builtin_amdgcn_s_setprio(1);
#pragma unroll
    for (int m = 0; m < 4; m++)
#pragma unroll
      for (int n = 0; n < 4; n++)
        acc[m][n] = __builtin_amdgcn_mfma_f32_16x16x32_bf16(afrag[m], bfrag[n], acc[m][n], 0, 0, 0);
    __builtin_amdgcn_s_setprio(0);
#pragma unroll
    for (int m = 0; m < 4; m++)
      afrag[m] = *(const bf16x8*)&as[(wr * 128 + (m + 4) * 16 + fr) * BK + g * 8];
    __builtin_amdgcn_s_setprio(1);
#pragma unroll
    for (int m = 0; m < 4; m++)
#pragma unroll
      for (int n = 0; n < 4; n++)
        acc[m + 4][n] = __builtin_amdgcn_mfma_f32_16x16x32_bf16(afrag[m], bfrag[n], acc[m + 4][n], 0, 0, 0);
    __builtin_amdgcn_s_setprio(0);

    // gate: K-tile t+1 fully landed (t+2's LPT loads stay in flight)
    asm volatile("s_waitcnt vmcnt(%0)" ::"n"(LPT) : "memory");
    __builtin_amdgcn_s_barrier();
    __builtin_amdgcn_sched_barrier(0);
    cur = nxt;
  }

#pragma unroll
  for (int m = 0; m < 8; m++) {
    int rbase = bm + wr * 128 + m * 16 + g * 4;
#pragma unroll
    for (int n = 0; n < 4; n++) {
      int col = bn + wc * 64 + n * 16 + fr;
#pragma unroll
      for (int r = 0; r < 4; r++)
        storeC(C, (size_t)(rbase + r) * N + col, acc[m][n][r] * oscale);
    }
  }
}

// ---------------- fused flash attention (v3) ----------------
__global__ __launch_bounds__(256) void attn_kernel(const u16* __restrict__ Q,
                                                   const u16* __restrict__ KV,
                                                   const u16* __restrict__ VT,
                                                   u16* __restrict__ O) {
  const int SQ = 2048, SKV = 1024;
  const int NCHUNK = SKV / 64;
  int qt = blockIdx.x & 15, bh = blockIdx.x >> 4;
  int b = bh >> 4, h = bh & 15;
  int wave = threadIdx.x >> 6, lane = threadIdx.x & 63;
  int q0 = qt * 128 + wave * 32;
  int fr = lane & 15, g = lane >> 4, fkb = g * 8;

  __shared__ __attribute__((aligned(16))) u16 Ks[2][64 * 128];
  __shared__ __attribute__((aligned(16))) u16 Pb[4][32 * 72];
  u16* P = &Pb[wave][0];

  bf16x8 qf[2][4];
#pragma unroll
  for (int gq = 0; gq < 2; gq++) {
    const u16* Qbase = Q + (size_t)(b * SQ + q0 + gq * 16 + fr) * 2048 + h * 128;
#pragma unroll
    for (int kd = 0; kd < 4; kd++)
      qf[gq][kd] = *(const bf16x8*)(Qbase + kd * 32 + fkb);
  }

  const u16* Kb = KV + (size_t)(b * SKV) * 4096 + h * 128;
  const u16* Vt = VT + (size_t)bh * (128 * 1024);

  auto stage = [&](int c, int buf) {
#pragma unroll
    for (int j = 0; j < 4; j++) {
      int r = wave * 16 + j * 4 + g;
      int gb = (lane & 15) ^ (r & 7);
      gload_lds16(Kb + (size_t)(c * 64 + r) * 4096 + gb * 8,
                  &Ks[buf][(wave * 16 + j * 4) * 128]);
    }
  };

  f32x4 o[2][8] = {};
  float mrun[2][4] = {{-1e30f, -1e30f, -1e30f, -1e30f},
                      {-1e30f, -1e30f, -1e30f, -1e30f}};
  float lrun[2][4] = {};

  stage(0, 0);
  __syncthreads();
  int buf = 0;

  for (int c = 0; c < NCHUNK; c++) {
    if (c + 1 < NCHUNK) stage(c + 1, buf ^ 1);

    f32x4 acc[2][4] = {};
#pragma unroll
    for (int n = 0; n < 4; n++) {
      int row = n * 16 + fr;
#pragma unroll
      for (int kd = 0; kd < 4; kd++) {
        int pb = (kd * 4 + g) ^ (fr & 7);
        bf16x8 kf = *(const bf16x8*)&Ks[buf][row * 128 + pb * 8];
        acc[0][n] = __builtin_amdgcn_mfma_f32_16x16x32_bf16(qf[0][kd], kf, acc[0][n], 0, 0, 0);
        acc[1][n] = __builtin_amdgcn_mfma_f32_16x16x32_bf16(qf[1][kd], kf, acc[1][n], 0, 0, 0);
      }
    }

    bf16x8 vf0[8], vf1[8];
#pragma unroll
    for (int nn = 0; nn < 8; nn++) {
      const u16* vrow = Vt + (size_t)(nn * 16 + fr) * 1024 + c * 64 + fkb;
      vf0[nn] = *(const bf16x8*)(vrow);
      vf1[nn] = *(const bf16x8*)(vrow + 32);
    }

    float corr[2][4];
#pragma unroll
    for (int gq = 0; gq < 2; gq++) {
#pragma unroll
      for (int r = 0; r < 4; r++) {
        float pm = fmaxf(fmaxf(acc[gq][0][r], acc[gq][1][r]),
                         fmaxf(acc[gq][2][r], acc[gq][3][r]));
#pragma unroll
        for (int off = 1; off < 16; off <<= 1) pm = fmaxf(pm, __shfl_xor(pm, off));
        float mn = fmaxf(mrun[gq][r], pm);
        corr[gq][r] = __expf(mrun[gq][r] - mn);
        mrun[gq][r] = mn;
        float psum = 0.f;
        int qrow = gq * 16 + g * 4 + r;
#pragma unroll
        for (int n = 0; n < 4; n++) {
          float p = __expf(acc[gq][n][r] - mn);
          psum += p;
          P[qrow * 72 + n * 16 + fr] = f2bf(p);
        }
        lrun[gq][r] = lrun[gq][r] * corr[gq][r] + psum;
      }
    }
#pragma unroll
    for (int gq = 0; gq < 2; gq++)
#pragma unroll
      for (int nn = 0; nn < 8; nn++) {
        o[gq][nn][0] *= corr[gq][0]; o[gq][nn][1] *= corr[gq][1];
        o[gq][nn][2] *= corr[gq][2]; o[gq][nn][3] *= corr[gq][3];
      }

    asm volatile("s_waitcnt lgkmcnt(0)" ::: "memory");
    {
      bf16x8 pa0 = *(const bf16x8*)&P[fr * 72 + fkb];
      bf16x8 pa1 = *(const bf16x8*)&P[(16 + fr) * 72 + fkb];
#pragma unroll
      for (int nn = 0; nn < 8; nn++) {
        o[0][nn] = __builtin_amdgcn_mfma_f32_16x16x32_bf16(pa0, vf0[nn], o[0][nn], 0, 0, 0);
        o[1][nn] = __builtin_amdgcn_mfma_f32_16x16x32_bf16(pa1, vf0[nn], o[1][nn], 0, 0, 0);
      }
      pa0 = *(const bf16x8*)&P[fr * 72 + 32 + fkb];
      pa1 = *(const bf16x8*)&P[(16 + fr) * 72 + 32 + fkb];
#pragma unroll
      for (int nn = 0; nn < 8; nn++) {
        o[0][nn] = __builtin_amdgcn_mfma_f32_16x16x32_bf16(pa0, vf1[nn], o[0][nn], 0, 0, 0);
        o[1][nn] = __builtin_amdgcn_mfma_f32_16x16x32_bf16(pa1, vf1[nn], o[1][nn], 0, 0, 0);
      }
    }

    __syncthreads();
    buf ^= 1;
  }

#pragma unroll
  for (int gq = 0; gq < 2; gq++)
#pragma unroll
    for (int r = 0; r < 4; r++) {
      float lt = lrun[gq][r];
#pragma unroll
      for (int off = 1; off < 16; off <<= 1) lt += __shfl_xor(lt, off);
      float inv = 1.0f / lt;
      int row = b * SQ + q0 + gq * 16 + g * 4 + r;
      u16* Or = O + (size_t)row * 2048 + h * 128;
#pragma unroll
      for (int nn = 0; nn < 8; nn++) Or[nn * 16 + fr] = f2bf(o[gq][nn][r] * inv);
    }
}

// ---------------- launch ----------------
extern "C" void kernel_launch(void* const* d_in, const int* in_sizes, int n_in,
                              void* d_out, int out_size, void* d_ws, size_t ws_size,
                              hipStream_t stream) {
  const float* image_embeds  = (const float*)d_in[0];  // [2,1024,2048]
  const float* hidden_states = (const float*)d_in[1];  // [2,2048,3072]
  const float* Wq   = (const float*)d_in[2];           // [3072,2048]
  const float* Wkv  = (const float*)d_in[3];           // [2048,4096]
  const float* Wout = (const float*)d_in[4];           // [2048,3072]
  const float* ln1_g = (const float*)d_in[5];
  const float* ln1_b = (const float*)d_in[6];
  const float* ln2_g = (const float*)d_in[7];
  const float* ln2_b = (const float*)d_in[8];
  float* out = (float*)d_out;

  char* ws = (char*)d_ws;
  size_t off = 0;
  auto alloc = [&](size_t bytes) {
    void* p = ws + off;
    off += (bytes + 255) & ~(size_t)255;
    return p;
  };
  u16* Xq   = (u16*)alloc((size_t)4096 * 3072 * 2);  // LN(hidden) bf16; reused as AO
  u16* Xkv  = (u16*)alloc((size_t)2048 * 2048 * 2);  // LN(image) bf16
  u16* WqT  = (u16*)alloc((size_t)2048 * 3072 * 2);  // Wq^T bf16; reused as VT
  u16* WkvT = (u16*)alloc((size_t)4096 * 2048 * 2);  // Wkv^T bf16
  u16* WoT  = (u16*)alloc((size_t)3072 * 2048 * 2);  // Wout^T bf16
  u16* Qb   = (u16*)alloc((size_t)4096 * 2048 * 2);  // q bf16 (pre-scaled)
  u16* KVb  = (u16*)alloc((size_t)2048 * 4096 * 2);  // kv bf16
  u16* VTb  = WqT;   // alias: WqT dead after q-gemm
  u16* AO   = Xq;    // alias: Xq dead after q-gemm

  const float qscale = 0.08838834764831845f;  // 1/sqrt(128)

  ln_cast<3><<<4096, 256, 0, stream>>>(hidden_states, ln2_g, ln2_b, Xq, 3072);
  ln_cast<2><<<2048, 256, 0, stream>>>(image_embeds, ln1_g, ln1_b, Xkv, 2048);
  transpose_cast<<<dim3(2048 / 32, 3072 / 32), 256, 0, stream>>>(Wq, WqT, 3072, 2048);
  transpose_cast<<<dim3(4096 / 32, 2048 / 32), 256, 0, stream>>>(Wkv, WkvT, 2048, 4096);
  transpose_cast<<<dim3(3072 / 32, 2048 / 32), 256, 0, stream>>>(Wout, WoT, 2048, 3072);

  // q: 4096x2048 (K=3072) -> 32x8 = 256 blocks
  gemm_pipe<u16, 128, 256, 1, 4><<<(4096 / 128) * (2048 / 256), 256, 0, stream>>>(
      Xq, WqT, Qb, 4096, 2048, 3072, qscale);
  // kv: 2048x4096 (K=2048) -> 16x16 = 256 blocks
  gemm_pipe<u16, 128, 256, 1, 4><<<(2048 / 128) * (4096 / 256), 256, 0, stream>>>(
      Xkv, WkvT, KVb, 2048, 4096, 2048, 1.0f);

  build_vt<<<dim3(4, 32, 32), 256, 0, stream>>>(KVb, VTb);
  attn_kernel<<<512, 256, 0, stream>>>(Qb, KVb, VTb, AO);

  // out: 4096x3072 (K=2048) -> 16x12 = 192 blocks, 256^2 tile, 8 waves
  gemm_pipe<float, 256, 256, 2, 4><<<(4096 / 256) * (3072 / 256), 512, 0, stream>>>(
      AO, WoT, out, 4096, 3072, 2048, 1.0f);
}

// Round 5
// 351.513 us; speedup vs baseline: 1.2051x; 1.2051x over previous
//
#include <hip/hip_runtime.h>
#include <hip/hip_bf16.h>

typedef unsigned short u16;
typedef __attribute__((ext_vector_type(8))) __bf16 bf16x8;
typedef __attribute__((ext_vector_type(4))) float f32x4;
typedef __attribute__((ext_vector_type(2))) unsigned int u32x2;

#define DEV __device__ __forceinline__

DEV u16 f2bf(float f) {
  union { float f; unsigned int u; } v; v.f = f;
  unsigned int x = v.u;
  return (u16)((x + 0x7fffu + ((x >> 16) & 1u)) >> 16);  // RNE
}

DEV void gload_lds16(const u16* g, u16* l) {
  __builtin_amdgcn_global_load_lds(
      (__attribute__((address_space(1))) void*)(g),
      (__attribute__((address_space(3))) void*)(l), 16, 0, 0);
}

// ---------------- LayerNorm + cast to bf16 ----------------
template <int NV>
__global__ __launch_bounds__(256) void ln_cast(const float* __restrict__ x,
                                               const float* __restrict__ g,
                                               const float* __restrict__ b,
                                               u16* __restrict__ out, int C) {
  int row = blockIdx.x;
  int tid = threadIdx.x;
  const float4* xr = (const float4*)(x + (size_t)row * C);
  float4 v[NV];
  float s = 0.f, ss = 0.f;
#pragma unroll
  for (int i = 0; i < NV; i++) {
    v[i] = xr[tid + i * 256];
    s += v[i].x + v[i].y + v[i].z + v[i].w;
    ss += v[i].x * v[i].x + v[i].y * v[i].y + v[i].z * v[i].z + v[i].w * v[i].w;
  }
#pragma unroll
  for (int off = 32; off > 0; off >>= 1) {
    s += __shfl_down(s, off);
    ss += __shfl_down(ss, off);
  }
  __shared__ float red[8];
  int wv = tid >> 6;
  if ((tid & 63) == 0) { red[wv] = s; red[4 + wv] = ss; }
  __syncthreads();
  float S = red[0] + red[1] + red[2] + red[3];
  float SS = red[4] + red[5] + red[6] + red[7];
  float mu = S / C;
  float rstd = rsqrtf(SS / C - mu * mu + 1e-5f);
  const float4* gr = (const float4*)g;
  const float4* br = (const float4*)b;
  ushort4* orow = (ushort4*)(out + (size_t)row * C);
#pragma unroll
  for (int i = 0; i < NV; i++) {
    int gi = tid + i * 256;
    float4 gv = gr[gi], bv = br[gi];
    ushort4 o;
    o.x = f2bf((v[i].x - mu) * rstd * gv.x + bv.x);
    o.y = f2bf((v[i].y - mu) * rstd * gv.y + bv.y);
    o.z = f2bf((v[i].z - mu) * rstd * gv.z + bv.z);
    o.w = f2bf((v[i].w - mu) * rstd * gv.w + bv.w);
    orow[gi] = o;
  }
}

// ---------------- transpose + cast f32 -> bf16 ----------------
__global__ __launch_bounds__(256) void transpose_cast(const float* __restrict__ in,
                                                      u16* __restrict__ out,
                                                      int K, int N) {
  __shared__ float t[32][33];
  int tx = threadIdx.x & 31, ty = threadIdx.x >> 5;
  int n0 = blockIdx.x * 32, k0 = blockIdx.y * 32;
#pragma unroll
  for (int i = 0; i < 32; i += 8)
    t[ty + i][tx] = in[(size_t)(k0 + ty + i) * N + n0 + tx];
  __syncthreads();
#pragma unroll
  for (int i = 0; i < 32; i += 8)
    out[(size_t)(n0 + ty + i) * K + k0 + tx] = f2bf(t[tx][ty + i]);
}

// ---------------- build VT[bh][128][1024] from KV ----------------
__global__ __launch_bounds__(256) void build_vt(const u16* __restrict__ KV,
                                                u16* __restrict__ VT) {
  __shared__ u16 t[32][33];
  int bh = blockIdx.z, b = bh >> 4, h = bh & 15;
  int d0 = blockIdx.x * 32, s0 = blockIdx.y * 32;
  int tx = threadIdx.x & 31, ty = threadIdx.x >> 5;
  const u16* src = KV + (size_t)(b * 1024) * 4096 + 2048 + h * 128;
#pragma unroll
  for (int i = 0; i < 32; i += 8)
    t[ty + i][tx] = src[(size_t)(s0 + ty + i) * 4096 + d0 + tx];
  __syncthreads();
  u16* dst = VT + (size_t)bh * (128 * 1024);
#pragma unroll
  for (int i = 0; i < 32; i += 8)
    dst[(size_t)(d0 + ty + i) * 1024 + s0 + tx] = t[tx][ty + i];
}

// ---------------- GEMM: C[M,N] = oscale * A[M,K] * BT[N,K]^T ----------------
DEV void storeC(u16* C, size_t idx, float v) { C[idx] = f2bf(v); }
DEV void storeC(float* C, size_t idx, float v) { C[idx] = v; }

template <typename OutT>
__global__ __launch_bounds__(256) void gemm_bt(const u16* __restrict__ A,
                                               const u16* __restrict__ BT,
                                               OutT* __restrict__ C,
                                               int M, int N, int K, float oscale) {
  constexpr int BK = 32;
  __shared__ __attribute__((aligned(16))) u16 As[128 * BK];
  __shared__ __attribute__((aligned(16))) u16 Bs[128 * BK];
  int tilesN = N >> 7;
  int bm = (blockIdx.x / tilesN) << 7;
  int bn = (blockIdx.x % tilesN) << 7;
  int tid = threadIdx.x;
  int lane = tid & 63, wave = tid >> 6;
  int wm = (wave >> 1) << 6, wn = (wave & 1) << 6;
  int srow = wave * 16 + (lane >> 2);
  int scol = (lane & 3) * 8;
  int fr = lane & 15, fk = (lane >> 4) * 8;
  const u16* Ab = A + (size_t)bm * K;
  const u16* Bb = BT + (size_t)bn * K;
  f32x4 acc[4][4] = {};

  for (int kt = 0; kt < K; kt += BK) {
#pragma unroll
    for (int j = 0; j < 2; j++) {
      gload_lds16(Ab + (size_t)(j * 64 + srow) * K + kt + scol,
                  &As[(j * 64 + wave * 16) * BK]);
      gload_lds16(Bb + (size_t)(j * 64 + srow) * K + kt + scol,
                  &Bs[(j * 64 + wave * 16) * BK]);
    }
    __syncthreads();
    bf16x8 af[4], bfr[4];
#pragma unroll
    for (int m = 0; m < 4; m++)
      af[m] = *(const bf16x8*)&As[(wm + m * 16 + fr) * BK + fk];
#pragma unroll
    for (int n = 0; n < 4; n++)
      bfr[n] = *(const bf16x8*)&Bs[(wn + n * 16 + fr) * BK + fk];
#pragma unroll
    for (int m = 0; m < 4; m++)
#pragma unroll
      for (int n = 0; n < 4; n++)
        acc[m][n] = __builtin_amdgcn_mfma_f32_16x16x32_bf16(af[m], bfr[n], acc[m][n], 0, 0, 0);
    __syncthreads();
  }

#pragma unroll
  for (int m = 0; m < 4; m++) {
    int rbase = bm + wm + m * 16 + ((lane >> 4) << 2);
#pragma unroll
    for (int n = 0; n < 4; n++) {
      int col = bn + wn + n * 16 + fr;
#pragma unroll
      for (int r = 0; r < 4; r++)
        storeC(C, (size_t)(rbase + r) * N + col, acc[m][n][r] * oscale);
    }
  }
}

// ---------------- fused flash attention (v4: swapped QK^T, in-lane softmax) ----------------
// 4 waves x 32 q-rows (2 q-groups of 16) = 128 q-rows per block.
// QK^T computed as mfma(K, Q) -> lane owns P[q=fr][16 kv values] per q-group:
// softmax max/sum mostly in-lane (2 shfl_xor for cross-g), P packed to LDS
// as 8B writes. PV reads P rows as before. grid = 512 blocks.
__global__ __launch_bounds__(256) void attn_kernel(const u16* __restrict__ Q,
                                                   const u16* __restrict__ KV,
                                                   const u16* __restrict__ VT,
                                                   u16* __restrict__ O) {
  const int SQ = 2048, SKV = 1024;
  const int NCHUNK = SKV / 64;
  int qt = blockIdx.x & 15, bh = blockIdx.x >> 4;
  int b = bh >> 4, h = bh & 15;
  int wave = threadIdx.x >> 6, lane = threadIdx.x & 63;
  int q0 = qt * 128 + wave * 32;
  int fr = lane & 15, g = lane >> 4, fkb = g * 8;

  __shared__ __attribute__((aligned(16))) u16 Ks[2][64 * 128];
  __shared__ __attribute__((aligned(16))) u16 Pb[4][32 * 72];  // row stride 72 (144B)
  u16* P = &Pb[wave][0];

  bf16x8 qf[2][4];
#pragma unroll
  for (int gq = 0; gq < 2; gq++) {
    const u16* Qbase = Q + (size_t)(b * SQ + q0 + gq * 16 + fr) * 2048 + h * 128;
#pragma unroll
    for (int kd = 0; kd < 4; kd++)
      qf[gq][kd] = *(const bf16x8*)(Qbase + kd * 32 + fkb);
  }

  const u16* Kb = KV + (size_t)(b * SKV) * 4096 + h * 128;
  const u16* Vt = VT + (size_t)bh * (128 * 1024);

  auto stage = [&](int c, int buf) {
#pragma unroll
    for (int j = 0; j < 4; j++) {
      int r = wave * 16 + j * 4 + g;
      int gb = (lane & 15) ^ (r & 7);
      gload_lds16(Kb + (size_t)(c * 64 + r) * 4096 + gb * 8,
                  &Ks[buf][(wave * 16 + j * 4) * 128]);
    }
  };

  f32x4 o[2][8] = {};
  float mrun[2] = {-1e30f, -1e30f};
  float lrun[2] = {0.f, 0.f};

  stage(0, 0);
  __syncthreads();
  int buf = 0;

  for (int c = 0; c < NCHUNK; c++) {
    if (c + 1 < NCHUNK) stage(c + 1, buf ^ 1);

    // swapped QK^T: acc[q_t][kv_t][r] = S[q = q_t*16 + fr][kv = kv_t*16 + g*4 + r]
    f32x4 acc[2][4] = {};
#pragma unroll
    for (int kv_t = 0; kv_t < 4; kv_t++) {
      int row = kv_t * 16 + fr;
#pragma unroll
      for (int kd = 0; kd < 4; kd++) {
        int pb = (kd * 4 + g) ^ (fr & 7);
        bf16x8 kf = *(const bf16x8*)&Ks[buf][row * 128 + pb * 8];
        acc[0][kv_t] = __builtin_amdgcn_mfma_f32_16x16x32_bf16(kf, qf[0][kd], acc[0][kv_t], 0, 0, 0);
        acc[1][kv_t] = __builtin_amdgcn_mfma_f32_16x16x32_bf16(kf, qf[1][kd], acc[1][kv_t], 0, 0, 0);
      }
    }

    // prefetch V for this chunk (latency hides under softmax)
    bf16x8 vf0[8], vf1[8];
#pragma unroll
    for (int nn = 0; nn < 8; nn++) {
      const u16* vrow = Vt + (size_t)(nn * 16 + fr) * 1024 + c * 64 + fkb;
      vf0[nn] = *(const bf16x8*)(vrow);
      vf1[nn] = *(const bf16x8*)(vrow + 32);
    }

    // online softmax: per lane, q = q_t*16 + fr, 16 kv values in-lane
    float corr[2];
#pragma unroll
    for (int q_t = 0; q_t < 2; q_t++) {
      float pm = fmaxf(fmaxf(fmaxf(acc[q_t][0][0], acc[q_t][0][1]), fmaxf(acc[q_t][0][2], acc[q_t][0][3])),
                       fmaxf(fmaxf(acc[q_t][1][0], acc[q_t][1][1]), fmaxf(acc[q_t][1][2], acc[q_t][1][3])));
      pm = fmaxf(pm, fmaxf(fmaxf(fmaxf(acc[q_t][2][0], acc[q_t][2][1]), fmaxf(acc[q_t][2][2], acc[q_t][2][3])),
                           fmaxf(fmaxf(acc[q_t][3][0], acc[q_t][3][1]), fmaxf(acc[q_t][3][2], acc[q_t][3][3]))));
      pm = fmaxf(pm, __shfl_xor(pm, 16));
      pm = fmaxf(pm, __shfl_xor(pm, 32));
      float mn = fmaxf(mrun[q_t], pm);
      corr[q_t] = __expf(mrun[q_t] - mn);
      mrun[q_t] = mn;
      float psum = 0.f;
#pragma unroll
      for (int kv_t = 0; kv_t < 4; kv_t++) {
        float p0 = __expf(acc[q_t][kv_t][0] - mn);
        float p1 = __expf(acc[q_t][kv_t][1] - mn);
        float p2 = __expf(acc[q_t][kv_t][2] - mn);
        float p3 = __expf(acc[q_t][kv_t][3] - mn);
        psum += (p0 + p1) + (p2 + p3);
        union { __hip_bfloat162 h; unsigned int u; } lo, hi;
        lo.h = __float22bfloat162_rn(make_float2(p0, p1));
        hi.h = __float22bfloat162_rn(make_float2(p2, p3));
        u32x2 w = {lo.u, hi.u};
        *(u32x2*)&P[(q_t * 16 + fr) * 72 + kv_t * 16 + g * 4] = w;
      }
      lrun[q_t] = lrun[q_t] * corr[q_t] + psum;
    }

    // redistribute corr to the PV/output layout: o-row q = gq*16 + g*4 + r
    float corr_o[2][4];
#pragma unroll
    for (int gq = 0; gq < 2; gq++)
#pragma unroll
      for (int r = 0; r < 4; r++)
        corr_o[gq][r] = __shfl(corr[gq], g * 4 + r);
#pragma unroll
    for (int gq = 0; gq < 2; gq++)
#pragma unroll
      for (int nn = 0; nn < 8; nn++) {
        o[gq][nn][0] *= corr_o[gq][0]; o[gq][nn][1] *= corr_o[gq][1];
        o[gq][nn][2] *= corr_o[gq][2]; o[gq][nn][3] *= corr_o[gq][3];
      }

    // PV (P per-wave in LDS; drain ds_writes before reading)
    asm volatile("s_waitcnt lgkmcnt(0)" ::: "memory");
    {
      bf16x8 pa0 = *(const bf16x8*)&P[fr * 72 + fkb];
      bf16x8 pa1 = *(const bf16x8*)&P[(16 + fr) * 72 + fkb];
#pragma unroll
      for (int nn = 0; nn < 8; nn++) {
        o[0][nn] = __builtin_amdgcn_mfma_f32_16x16x32_bf16(pa0, vf0[nn], o[0][nn], 0, 0, 0);
        o[1][nn] = __builtin_amdgcn_mfma_f32_16x16x32_bf16(pa1, vf0[nn], o[1][nn], 0, 0, 0);
      }
      pa0 = *(const bf16x8*)&P[fr * 72 + 32 + fkb];
      pa1 = *(const bf16x8*)&P[(16 + fr) * 72 + 32 + fkb];
#pragma unroll
      for (int nn = 0; nn < 8; nn++) {
        o[0][nn] = __builtin_amdgcn_mfma_f32_16x16x32_bf16(pa0, vf1[nn], o[0][nn], 0, 0, 0);
        o[1][nn] = __builtin_amdgcn_mfma_f32_16x16x32_bf16(pa1, vf1[nn], o[1][nn], 0, 0, 0);
      }
    }

    __syncthreads();
    buf ^= 1;
  }

  // final l: sum across g-lanes (q = q_t*16+fr), then redistribute to o layout
#pragma unroll
  for (int q_t = 0; q_t < 2; q_t++) {
    float lt = lrun[q_t];
    lt += __shfl_xor(lt, 16);
    lt += __shfl_xor(lt, 32);
    lrun[q_t] = lt;
  }
#pragma unroll
  for (int gq = 0; gq < 2; gq++)
#pragma unroll
    for (int r = 0; r < 4; r++) {
      float lt = __shfl(lrun[gq], g * 4 + r);
      float inv = 1.0f / lt;
      int row = b * SQ + q0 + gq * 16 + g * 4 + r;
      u16* Or = O + (size_t)row * 2048 + h * 128;
#pragma unroll
      for (int nn = 0; nn < 8; nn++) Or[nn * 16 + fr] = f2bf(o[gq][nn][r] * inv);
    }
}

// ---------------- launch ----------------
extern "C" void kernel_launch(void* const* d_in, const int* in_sizes, int n_in,
                              void* d_out, int out_size, void* d_ws, size_t ws_size,
                              hipStream_t stream) {
  const float* image_embeds  = (const float*)d_in[0];  // [2,1024,2048]
  const float* hidden_states = (const float*)d_in[1];  // [2,2048,3072]
  const float* Wq   = (const float*)d_in[2];           // [3072,2048]
  const float* Wkv  = (const float*)d_in[3];           // [2048,4096]
  const float* Wout = (const float*)d_in[4];           // [2048,3072]
  const float* ln1_g = (const float*)d_in[5];
  const float* ln1_b = (const float*)d_in[6];
  const float* ln2_g = (const float*)d_in[7];
  const float* ln2_b = (const float*)d_in[8];
  float* out = (float*)d_out;

  char* ws = (char*)d_ws;
  size_t off = 0;
  auto alloc = [&](size_t bytes) {
    void* p = ws + off;
    off += (bytes + 255) & ~(size_t)255;
    return p;
  };
  u16* Xq   = (u16*)alloc((size_t)4096 * 3072 * 2);  // LN(hidden) bf16; reused as AO
  u16* Xkv  = (u16*)alloc((size_t)2048 * 2048 * 2);  // LN(image) bf16
  u16* WqT  = (u16*)alloc((size_t)2048 * 3072 * 2);  // Wq^T bf16; reused as VT
  u16* WkvT = (u16*)alloc((size_t)4096 * 2048 * 2);  // Wkv^T bf16
  u16* WoT  = (u16*)alloc((size_t)3072 * 2048 * 2);  // Wout^T bf16
  u16* Qb   = (u16*)alloc((size_t)4096 * 2048 * 2);  // q bf16 (pre-scaled)
  u16* KVb  = (u16*)alloc((size_t)2048 * 4096 * 2);  // kv bf16
  u16* VTb  = WqT;   // alias: WqT dead after q-gemm
  u16* AO   = Xq;    // alias: Xq dead after q-gemm

  const float qscale = 0.08838834764831845f;  // 1/sqrt(128)

  ln_cast<3><<<4096, 256, 0, stream>>>(hidden_states, ln2_g, ln2_b, Xq, 3072);
  ln_cast<2><<<2048, 256, 0, stream>>>(image_embeds, ln1_g, ln1_b, Xkv, 2048);
  transpose_cast<<<dim3(2048 / 32, 3072 / 32), 256, 0, stream>>>(Wq, WqT, 3072, 2048);
  transpose_cast<<<dim3(4096 / 32, 2048 / 32), 256, 0, stream>>>(Wkv, WkvT, 2048, 4096);
  transpose_cast<<<dim3(3072 / 32, 2048 / 32), 256, 0, stream>>>(Wout, WoT, 2048, 3072);

  gemm_bt<u16><<<(4096 / 128) * (2048 / 128), 256, 0, stream>>>(Xq, WqT, Qb, 4096, 2048, 3072, qscale);
  gemm_bt<u16><<<(2048 / 128) * (4096 / 128), 256, 0, stream>>>(Xkv, WkvT, KVb, 2048, 4096, 2048, 1.0f);

  build_vt<<<dim3(4, 32, 32), 256, 0, stream>>>(KVb, VTb);
  attn_kernel<<<512, 256, 0, stream>>>(Qb, KVb, VTb, AO);

  gemm_bt<float><<<(4096 / 128) * (3072 / 128), 256, 0, stream>>>(AO, WoT, out, 4096, 3072, 2048, 1.0f);
}